// Round 4
// baseline (1205.128 us; speedup 1.0000x reference)
//
#include <hip/hip_runtime.h>
#include <stdint.h>

#define TT 512

typedef __fp16   f16x8  __attribute__((ext_vector_type(8)));
typedef float    f32x4  __attribute__((ext_vector_type(4)));
typedef __fp16   fp16x2 __attribute__((ext_vector_type(2)));
typedef uint32_t u32x4  __attribute__((ext_vector_type(4)));

__device__ __forceinline__ f32x4 mfma16(f16x8 a, f16x8 b, f32x4 c) {
    return __builtin_amdgcn_mfma_f32_16x16x32_f16(a, b, c, 0, 0, 0);
}
__device__ __forceinline__ uint32_t pkf16(float a, float b) {
    fp16x2 h = __builtin_amdgcn_cvt_pkrtz(a, b);
    return __builtin_bit_cast(uint32_t, h);
}

// Spin-wait on a progress counter (workgroup-scope LDS atomic, cached locally).
// Steady state: producer runs ~8 ahead -> cache jumps, ~1 reload per 8 steps.
#define WAITGE(cache, idx, need) \
  while ((cache) < (need)) \
    (cache) = __hip_atomic_load(&Pf[idx], __ATOMIC_ACQUIRE, __HIP_MEMORY_SCOPE_WORKGROUP);

// R15: FULL-LAYER WAVE OWNERSHIP. R14 (+7% only) showed the recurrence bottleneck
// is the intra-layer cross-wave h exchange through LDS (write+flag+poll+read
// ~400cy on the 512-step serial chain). Now: 1 wave = 1 layer = 16 rows x 64 units
// x 256 z-cols; h stays IN REGISTERS across steps. Weight-column permutation baked
// into the gather makes MFMA C-output (m=4*quad+r) land on h-units {8q..8q+7,
// 32+8q..+7} = exactly the next-step B-frag layout (k=8*quad+j) -> gate outputs
// pack straight into next B operands (cvt_pkrtz), zero LDS in the recurrence.
// Inter-layer: 8-slot lane-symmetric frag ring + cached flags (R14 protocol).
// zcol(G,g,m) = 64g + 32(G>>1) + 8(m>>2) + 4(G&1) + (m&3); unit(G,q,r) =
// 32(G>>1) + 8q + 4(G&1) + r. Bias/Wx0 read from LDS per step (VGPR budget).
__global__ __launch_bounds__(256)
__attribute__((amdgpu_waves_per_eu(1, 1)))
void lstm_owner(
    const float* __restrict__ x,
    const float* __restrict__ Wx0, const float* __restrict__ U0, const float* __restrict__ b0,
    const float* __restrict__ Wx1, const float* __restrict__ U1, const float* __restrict__ b1,
    const float* __restrict__ Wx2, const float* __restrict__ U2, const float* __restrict__ b2,
    const float* __restrict__ Wx3, const float* __restrict__ U3, const float* __restrict__ b3,
    const float* __restrict__ Wd,  const float* __restrict__ bd,
    float* __restrict__ out)
{
    // dwords: ring f16 [0,12288) | xs [12288,20992) | bs [20992,22016) | wxs [22016,22272) | Pf [22272,22276)
    extern __shared__ uint32_t smem[];
    __fp16* ring = (__fp16*)smem;               // [3 layers][8 slots][1024 f16] lane-keyed frags
    float*  xs   = (float*)(smem + 12288);      // [t 512][17]
    float*  bs   = (float*)(smem + 20992);      // [4][256] bias
    float*  wxs  = (float*)(smem + 22016);      // [256] Wx0 row
    int*    Pf   = (int*)(smem + 22272);        // [4] per-layer progress

    const int tid  = threadIdx.x;
    const int lane = tid & 63;
    const int l15  = lane & 15;
    const int quad = lane >> 4;
    const int l    = tid >> 6;                  // wave = layer
    const int b0i  = blockIdx.x * 16;

    // ---- staging (256 threads) ----
    for (int i = tid; i < 16 * TT; i += 256) {
        int row = i >> 9, t_ = i & (TT - 1);
        xs[t_ * 17 + row] = x[(b0i + row) * TT + t_];
    }
    for (int i = tid; i < 1024; i += 256) {
        const float* bsrc = (i < 256) ? b0 : (i < 512) ? b1 : (i < 768) ? b2 : b3;
        bs[i] = bsrc[i & 255];
    }
    wxs[tid] = Wx0[tid];
    if (tid < 4) Pf[tid] = 0;

    const float* Uw   = (l == 0) ? U0 : (l == 1) ? U1 : (l == 2) ? U2 : U3;
    const float* Wsrc = (l == 1) ? Wx1 : (l == 2) ? Wx2 : (l == 3) ? Wx3 : U0;

    // ---- weight fragments (permuted gather) ----
    f16x8 uA[4][4][2];
    f16x8 wA[4][4][2];
    #pragma unroll
    for (int G = 0; G < 4; ++G)
      #pragma unroll
      for (int g = 0; g < 4; ++g) {
        const int zc = 64*g + 32*(G>>1) + 8*(l15>>2) + 4*(G&1) + (l15&3);
        #pragma unroll
        for (int F = 0; F < 2; ++F) {
          f16x8 v;
          #pragma unroll
          for (int j = 0; j < 8; ++j) v[j] = (__fp16)Uw[(32*F + 8*quad + j)*256 + zc];
          uA[G][g][F] = v;
          if (l > 0) {
            f16x8 w2;
            #pragma unroll
            for (int j = 0; j < 8; ++j) w2[j] = (__fp16)Wsrc[(32*F + 8*quad + j)*256 + zc];
            wA[G][g][F] = w2;
          }
        }
      }

    f32x4 acc[4][4];
    f32x4 cst[4] = {};
    f32x4 hs[4]  = {};
    f16x8 hB0 = {}, hB1 = {};                   // own h (recurrence), in registers
    f16x8 xB0 = {}, xB1 = {};                   // upstream h_in frags

    __fp16*       rout = ring + l * 8192;       // own ring (l<3)
    const __fp16* rin  = ring + (l - 1) * 8192; // upstream (l>0)
    const float*  bsl  = bs + l * 256;

    __syncthreads();

    int pIn = 0, pOut = 0;

    for (int t = 0; t < TT; ++t) {
        float xvp = 0.f;
        if (l == 0) {
            xvp = xs[t * 17 + l15];
        } else {
            WAITGE(pIn, l - 1, t + 1)
            const __fp16* rp = rin + (t & 7) * 1024 + lane * 8;
            xB0 = *(const f16x8*)rp;
            xB1 = *(const f16x8*)(rp + 512);
        }
        if (l < 3 && t >= 8) WAITGE(pOut, l + 1, t - 7)

        // z = bias + W*in  (x-side)
        #pragma unroll
        for (int G = 0; G < 4; ++G)
          #pragma unroll
          for (int g = 0; g < 4; ++g) {
            const int bo = 64*g + 32*(G>>1) + 8*quad + 4*(G&1);
            f32x4 bv = *(const f32x4*)(bsl + bo);
            if (l == 0) {
                f32x4 wv = *(const f32x4*)(wxs + bo);
                acc[G][g] = bv + wv * xvp;
            } else {
                acc[G][g] = mfma16(wA[G][g][0], xB0, bv);
            }
          }
        if (l > 0) {
          #pragma unroll
          for (int G = 0; G < 4; ++G)
            #pragma unroll
            for (int g = 0; g < 4; ++g)
              acc[G][g] = mfma16(wA[G][g][1], xB1, acc[G][g]);
        }
        // + U*h (recurrence, register B operands)
        #pragma unroll
        for (int G = 0; G < 4; ++G)
          #pragma unroll
          for (int g = 0; g < 4; ++g)
            acc[G][g] = mfma16(uA[G][g][0], hB0, acc[G][g]);
        #pragma unroll
        for (int G = 0; G < 4; ++G)
          #pragma unroll
          for (int g = 0; g < 4; ++g)
            acc[G][g] = mfma16(uA[G][g][1], hB1, acc[G][g]);

        // gates -> h packed straight into next-step B frags
        uint32_t w[8];
        const bool sv = (l == 3) && (t == TT - 1);
        #pragma unroll
        for (int G = 0; G < 4; ++G) {
            f32x4 Ai = acc[G][0], Af = acc[G][1], Ag = acc[G][2], Ao = acc[G][3];
            f32x4 ei, ef, eo;
            #pragma unroll
            for (int r = 0; r < 4; ++r) {
                ei[r] = __builtin_amdgcn_exp2f(-1.4426950408889634f * Ai[r]);
                ef[r] = __builtin_amdgcn_exp2f(-1.4426950408889634f * Af[r]);
                eo[r] = __builtin_amdgcn_exp2f(-1.4426950408889634f * Ao[r]);
            }
            f32x4 si, sf, so;
            #pragma unroll
            for (int r = 0; r < 4; ++r) {
                si[r] = __builtin_amdgcn_rcpf(1.0f + ei[r]);
                sf[r] = __builtin_amdgcn_rcpf(1.0f + ef[r]);
                so[r] = __builtin_amdgcn_rcpf(1.0f + eo[r]);
            }
            const f32x4 z4 = {0.f, 0.f, 0.f, 0.f};
            f32x4 rg = __builtin_elementwise_max(Ag, z4);
            f32x4 cv = sf * cst[G] + si * rg;
            cst[G] = cv;
            f32x4 hv = so * __builtin_elementwise_max(cv, z4);
            w[2*G + 0] = pkf16(hv[0], hv[1]);
            w[2*G + 1] = pkf16(hv[2], hv[3]);
            if (sv) hs[G] = hv;
        }
        u32x4 f0 = {w[0], w[1], w[2], w[3]};
        u32x4 f1 = {w[4], w[5], w[6], w[7]};
        hB0 = __builtin_bit_cast(f16x8, f0);
        hB1 = __builtin_bit_cast(f16x8, f1);
        if (l < 3) {                            // publish frags for layer l+1
            __fp16* wp = rout + (t & 7) * 1024 + lane * 8;
            *(u32x4*)wp = f0;
            *(u32x4*)(wp + 512) = f1;
        }
        __hip_atomic_store(&Pf[l], t + 1, __ATOMIC_RELEASE, __HIP_MEMORY_SCOPE_WORKGROUP);
    }

    // dense epilogue: wave 3 alone holds h[511] (f32 hs); units base = 8q+4(G&1)+32(G>>1)
    if (l == 3) {
        float p = 0.f;
        #pragma unroll
        for (int G = 0; G < 4; ++G) {
            const int ub = 8*quad + 4*(G&1) + 32*(G>>1);
            #pragma unroll
            for (int r = 0; r < 4; ++r) p += hs[G][r] * Wd[ub + r];
        }
        p += __shfl_down(p, 32, 64);
        p += __shfl_down(p, 16, 64);
        if (lane < 16) out[b0i + lane] = p + bd[0];
    }
}

extern "C" void kernel_launch(void* const* d_in, const int* in_sizes, int n_in,
                              void* d_out, int out_size, void* d_ws, size_t ws_size,
                              hipStream_t stream) {
    const float* x   = (const float*)d_in[0];
    const float* Wx0 = (const float*)d_in[1];
    const float* U0  = (const float*)d_in[2];
    const float* b0  = (const float*)d_in[3];
    const float* Wx1 = (const float*)d_in[4];
    const float* U1  = (const float*)d_in[5];
    const float* b1  = (const float*)d_in[6];
    const float* Wx2 = (const float*)d_in[7];
    const float* U2  = (const float*)d_in[8];
    const float* b2  = (const float*)d_in[9];
    const float* Wx3 = (const float*)d_in[10];
    const float* U3  = (const float*)d_in[11];
    const float* b3  = (const float*)d_in[12];
    const float* Wd  = (const float*)d_in[13];
    const float* bd  = (const float*)d_in[14];
    float* out = (float*)d_out;

    static const int kLds = 22276 * 4;   // 89104 B dynamic LDS
    (void)hipFuncSetAttribute((const void*)lstm_owner,
                              hipFuncAttributeMaxDynamicSharedMemorySize, kLds);
    hipLaunchKernelGGL(lstm_owner, dim3(64), dim3(256), kLds, stream,
                       x, Wx0, U0, b0, Wx1, U1, b1, Wx2, U2, b2, Wx3, U3, b3,
                       Wd, bd, out);
}

// Round 5
// 823.861 us; speedup vs baseline: 1.4628x; 1.4628x over previous
//
#include <hip/hip_runtime.h>
#include <stdint.h>

#define TT 512

typedef __fp16   f16x8  __attribute__((ext_vector_type(8)));
typedef float    f32x4  __attribute__((ext_vector_type(4)));
typedef __fp16   fp16x2 __attribute__((ext_vector_type(2)));
typedef uint32_t u32x2  __attribute__((ext_vector_type(2)));

__device__ __forceinline__ f32x4 mfma16(f16x8 a, f16x8 b, f32x4 c) {
    return __builtin_amdgcn_mfma_f32_16x16x32_f16(a, b, c, 0, 0, 0);
}
__device__ __forceinline__ uint32_t pkf16(float a, float b) {
    fp16x2 h = __builtin_amdgcn_cvt_pkrtz(a, b);
    return __builtin_bit_cast(uint32_t, h);
}

#define REP8(M) M(0)M(1)M(2)M(3)M(4)M(5)M(6)M(7)

// A-operand gather with per-column scale SC (weights transposed, z^T form):
// A[m=16T+l15][k=32F+8q+j] = SRC[k][16T+l15] * SC
#define GA(SRC, T, F, SC) (f16x8){ \
  (__fp16)((SRC)[(32*(F)+8*quad+0)*256 + 16*(T)+l15] * (SC)), \
  (__fp16)((SRC)[(32*(F)+8*quad+1)*256 + 16*(T)+l15] * (SC)), \
  (__fp16)((SRC)[(32*(F)+8*quad+2)*256 + 16*(T)+l15] * (SC)), \
  (__fp16)((SRC)[(32*(F)+8*quad+3)*256 + 16*(T)+l15] * (SC)), \
  (__fp16)((SRC)[(32*(F)+8*quad+4)*256 + 16*(T)+l15] * (SC)), \
  (__fp16)((SRC)[(32*(F)+8*quad+5)*256 + 16*(T)+l15] * (SC)), \
  (__fp16)((SRC)[(32*(F)+8*quad+6)*256 + 16*(T)+l15] * (SC)), \
  (__fp16)((SRC)[(32*(F)+8*quad+7)*256 + 16*(T)+l15] * (SC)) }

// Wave (l,h) owns zcols {64g + 32h + 16q' .. +15}: local j = 2g+q' -> tile Tg.
// R16: gate index = j>>1 (0:i 1:f 2:g 3:o). i/f/o columns+bias pre-scaled by
// -log2e so gates use exp2(z') directly (saves 24 VALU/wave/step + 1 chain stage).
#define DECLT(j) f16x8 uA##j##_0, uA##j##_1, wA##j##_0, wA##j##_1; f32x4 bias##j;
#define LOADT(j) { \
  const int Tg_ = ((j)>>1)*4 + 2*h + ((j)&1); \
  const float sc_ = (((j)>>1) == 2) ? 1.0f : -1.4426950408889634f; \
  uA##j##_0 = GA(Uw, Tg_, 0, sc_); uA##j##_1 = GA(Uw, Tg_, 1, sc_); \
  bias##j = (f32x4){ bw_[16*Tg_ + 4*quad + 0] * sc_, bw_[16*Tg_ + 4*quad + 1] * sc_, \
                     bw_[16*Tg_ + 4*quad + 2] * sc_, bw_[16*Tg_ + 4*quad + 3] * sc_ }; \
  if (l > 0) { wA##j##_0 = GA(Wsrc, Tg_, 0, sc_); wA##j##_1 = GA(Wsrc, Tg_, 1, sc_); } \
  else { wA##j##_0 = __builtin_bit_cast(f16x8, (f32x4){ \
           Wx0[16*Tg_+4*quad+0] * sc_, Wx0[16*Tg_+4*quad+1] * sc_, \
           Wx0[16*Tg_+4*quad+2] * sc_, Wx0[16*Tg_+4*quad+3] * sc_ }); \
         wA##j##_1 = wA##j##_0; } }

// W-side prefetch into wacc (off the recurrence critical path, runs post-publish)
#define DECLW(j) f32x4 wacc##j;
#define WPREP(j)  wacc##j = mfma16(wA##j##_0, xBp0, bias##j); \
                  wacc##j = mfma16(wA##j##_1, xBp1, wacc##j);
#define WPREPX(j) wacc##j = bias##j + __builtin_bit_cast(f32x4, wA##j##_0) * xvp4;

// U-burst: only 2 chained MFMAs on the recurrence path now.
#define MUA(j) acc##j = mfma16(uA##j##_0, hB0, wacc##j);
#define MUB(j) acc##j = mfma16(uA##j##_1, hB1, acc##j);

#define MFMA_SEG(t_) { \
  const __fp16* hp_ = hb_l + (((t_)-1)&7)*1152 + l15*72 + 8*quad; \
  f16x8 hB0 = *(const f16x8*)hp_; \
  f16x8 hB1 = *(const f16x8*)(hp_ + 32); \
  REP8(MUA) \
  REP8(MUB) }

// Gates: z' for i/f/o is pre-scaled -> exp2 direct; g unscaled (relu only).
#define GATES(qp, Ai, Af, Ag, Ao, CST, SAVEK, HK) { \
  f32x4 ei_, ef_, eo_; \
  _Pragma("unroll") for (int r_ = 0; r_ < 4; ++r_) { \
    ei_[r_] = __builtin_amdgcn_exp2f(Ai[r_]); \
    ef_[r_] = __builtin_amdgcn_exp2f(Af[r_]); \
    eo_[r_] = __builtin_amdgcn_exp2f(Ao[r_]); \
  } \
  f32x4 si_, sf_, so_; \
  _Pragma("unroll") for (int r_ = 0; r_ < 4; ++r_) { \
    si_[r_] = __builtin_amdgcn_rcpf(1.0f + ei_[r_]); \
    sf_[r_] = __builtin_amdgcn_rcpf(1.0f + ef_[r_]); \
    so_[r_] = __builtin_amdgcn_rcpf(1.0f + eo_[r_]); \
  } \
  const f32x4 z4_ = {0.f, 0.f, 0.f, 0.f}; \
  f32x4 rg_ = __builtin_elementwise_max(Ag, z4_); \
  f32x4 cv_ = sf_ * CST + si_ * rg_; \
  CST = cv_; \
  f32x4 hv_ = so_ * __builtin_elementwise_max(cv_, z4_); \
  u32x2 pv_ = { pkf16(hv_[0], hv_[1]), pkf16(hv_[2], hv_[3]) }; \
  *(u32x2*)(hw_ + 16*(qp)) = pv_; \
  if (SAVEK) HK = hv_; }

#define GATE_SEG(tg_, SV_) { \
  __fp16* hw_ = hb_l + ((tg_)&7)*1152 + l15*72 + 32*h + 4*quad; \
  GATES(0, acc0, acc2, acc4, acc6, cst0, SV_, hK0) \
  GATES(1, acc1, acc3, acc5, acc7, cst1, SV_, hK1) }

// Spin-wait on a progress counter (workgroup-scope LDS atomic, cached locally).
#define WAITGE(cache, idx, need) \
  while ((cache) < (need)) \
    (cache) = __hip_atomic_load(&Pf[idx], __ATOMIC_ACQUIRE, __HIP_MEMORY_SCOPE_WORKGROUP);

// 64 blocks x 512 threads; block = 16 batch rows; 8 waves = 4 layers x 2 unit-halves.
// R16 = R14 async-decoupled base (best, 594us steady) + critical-path shortening:
//  (1) W-side MFMAs hoisted OFF the recurrence chain (wacc prefetch post-publish;
//      chain now: partner-poll -> ds_read h -> 2 chained U-MFMAs -> gates -> publish)
//  (2) -log2e folded into i/f/o weight columns + biases (exp2 direct)
//  (3) setprio(1) around the U-burst (T5, async role-split regime)
// R15 lesson: 1 wave/SIMD serializes pipes (in-order issue) -> keep 2 waves/SIMD.
__global__ __launch_bounds__(512)
__attribute__((amdgpu_waves_per_eu(2, 2)))
void lstm_phase(
    const float* __restrict__ x,
    const float* __restrict__ Wx0, const float* __restrict__ U0, const float* __restrict__ b0,
    const float* __restrict__ Wx1, const float* __restrict__ U1, const float* __restrict__ b1,
    const float* __restrict__ Wx2, const float* __restrict__ U2, const float* __restrict__ b2,
    const float* __restrict__ Wx3, const float* __restrict__ U3, const float* __restrict__ b3,
    const float* __restrict__ Wd,  const float* __restrict__ bd,
    float* __restrict__ out)
{
    // dwords: hbuf f16 [0,18432) | x_s f32 [18432,27136) | red [27136,27168) | P [27168,27176)
    extern __shared__ uint32_t smem[];
    __fp16* hb16 = (__fp16*)smem;              // [l][slot8][row 16][unit 64 pad 72]
    float*  xs   = (float*)(smem + 18432);     // [t][17]
    float*  red  = (float*)(smem + 27136);     // [2][16] epilogue partials
    int*    Pf   = (int*)(smem + 27168);       // [8] per-wave progress counters

    const int tid  = threadIdx.x;
    const int lane = tid & 63;
    const int l15  = lane & 15;
    const int quad = lane >> 4;
    const int wv   = tid >> 6;
    const int l    = wv >> 1;                  // layer
    const int h    = wv & 1;                   // unit-half
    const int b0i  = blockIdx.x * 16;

    // ---- staging: zero hbuf + flags, stage x ----
    for (int i = tid; i < 27176; i += 512) smem[i] = 0;
    __syncthreads();
    for (int i = tid; i < 16 * TT; i += 512) {
        int row = i >> 9, t_ = i & (TT - 1);
        xs[t_ * 17 + row] = x[(b0i + row) * TT + t_];
    }

    const float* Uw   = (l == 0) ? U0 : (l == 1) ? U1 : (l == 2) ? U2 : U3;
    const float* bw_  = (l == 0) ? b0 : (l == 1) ? b1 : (l == 2) ? b2 : b3;
    const float* Wsrc = (l == 1) ? Wx1 : (l == 2) ? Wx2 : (l == 3) ? Wx3 : U0;

    REP8(DECLT)
    REP8(LOADT)
    REP8(DECLW)

    f32x4 acc0, acc1, acc2, acc3, acc4, acc5, acc6, acc7;
    f32x4 cst0 = {0,0,0,0}, cst1 = {0,0,0,0};
    f32x4 hK0  = {0,0,0,0}, hK1  = {0,0,0,0};

    __fp16* hb_l  = hb16 + l * 9216;           // own buffer (8 slots x 1152 f16)
    const __fp16* hb_in = hb16 + (l > 0 ? (l - 1) * 9216 : 0);

    f16x8 xBp0 = {}, xBp1 = {};

    __syncthreads();

    int pA0 = 0, pA1 = 0, pP = 0, pC0 = 0, pC1 = 0;   // cached counter values

    // ---- prologue: wacc for t=0 ----
    if (l == 0) {
        float xvp = xs[l15];
        f32x4 xvp4 = {xvp, xvp, xvp, xvp};
        REP8(WPREPX)
    } else {
        WAITGE(pA0, 2*l - 2, 1)
        WAITGE(pA1, 2*l - 1, 1)
        const __fp16* xp_ = hb_in + 0 * 1152 + l15 * 72 + 8 * quad;
        xBp0 = *(const f16x8*)xp_;
        xBp1 = *(const f16x8*)(xp_ + 32);
        REP8(WPREP)
    }

    for (int t = 0; t < TT; ++t) {
        if (t > 0) WAITGE(pP, 2*l + 1 - h, t)
        if (l < 3 && t >= 8) {                 // ring-reuse guard (slot t&7 = h(t-8))
            WAITGE(pC0, 2*l + 2, t - 7)
            WAITGE(pC1, 2*l + 3, t - 7)
        }
        __builtin_amdgcn_s_setprio(1);
        MFMA_SEG(t)
        __builtin_amdgcn_s_setprio(0);
        {
            const bool sv_ = (l == 3) && (t == TT - 1);
            GATE_SEG(t, sv_)
        }
        __hip_atomic_store(&Pf[2*l + h], t + 1, __ATOMIC_RELEASE, __HIP_MEMORY_SCOPE_WORKGROUP);

        // ---- W-side prefetch for t+1 (off the recurrence critical path) ----
        if (t + 1 < TT) {
            if (l == 0) {
                float xvp = xs[(t + 1) * 17 + l15];
                f32x4 xvp4 = {xvp, xvp, xvp, xvp};
                REP8(WPREPX)
            } else {
                WAITGE(pA0, 2*l - 2, t + 2)
                WAITGE(pA1, 2*l - 1, t + 2)
                const __fp16* xp_ = hb_in + ((t + 1) & 7) * 1152 + l15 * 72 + 8 * quad;
                xBp0 = *(const f16x8*)xp_;
                xBp1 = *(const f16x8*)(xp_ + 32);
                REP8(WPREP)
            }
        }
    }

    __syncthreads();

    // dense epilogue: waves (3,h); lane holds h[511] f32 for units 32h+16q'+4quad+r, row l15
    if (l == 3) {
        float p = 0.f;
        #pragma unroll
        for (int r = 0; r < 4; ++r) {
            p += hK0[r] * Wd[32 * h + 4 * quad + r];
            p += hK1[r] * Wd[32 * h + 16 + 4 * quad + r];
        }
        p += __shfl_down(p, 32, 64);
        p += __shfl_down(p, 16, 64);
        if (lane < 16) red[h * 16 + lane] = p;
    }
    __syncthreads();
    if (wv == 6 && lane < 16) out[b0i + lane] = red[lane] + red[16 + lane] + bd[0];
}

extern "C" void kernel_launch(void* const* d_in, const int* in_sizes, int n_in,
                              void* d_out, int out_size, void* d_ws, size_t ws_size,
                              hipStream_t stream) {
    const float* x   = (const float*)d_in[0];
    const float* Wx0 = (const float*)d_in[1];
    const float* U0  = (const float*)d_in[2];
    const float* b0  = (const float*)d_in[3];
    const float* Wx1 = (const float*)d_in[4];
    const float* U1  = (const float*)d_in[5];
    const float* b1  = (const float*)d_in[6];
    const float* Wx2 = (const float*)d_in[7];
    const float* U2  = (const float*)d_in[8];
    const float* b2  = (const float*)d_in[9];
    const float* Wx3 = (const float*)d_in[10];
    const float* U3  = (const float*)d_in[11];
    const float* b3  = (const float*)d_in[12];
    const float* Wd  = (const float*)d_in[13];
    const float* bd  = (const float*)d_in[14];
    float* out = (float*)d_out;

    static const int kLds = 27176 * 4;   // 108704 B dynamic LDS
    (void)hipFuncSetAttribute((const void*)lstm_phase,
                              hipFuncAttributeMaxDynamicSharedMemorySize, kLds);
    hipLaunchKernelGGL(lstm_phase, dim3(64), dim3(512), kLds, stream,
                       x, Wx0, U0, b0, Wx1, U1, b1, Wx2, U2, b2, Wx3, U3, b3,
                       Wd, bd, out);
}

// Round 6
// 680.039 us; speedup vs baseline: 1.7721x; 1.2115x over previous
//
#include <hip/hip_runtime.h>
#include <stdint.h>

#define TT 512

typedef __fp16   f16x8  __attribute__((ext_vector_type(8)));
typedef float    f32x4  __attribute__((ext_vector_type(4)));
typedef __fp16   fp16x2 __attribute__((ext_vector_type(2)));
typedef uint32_t u32x2  __attribute__((ext_vector_type(2)));

__device__ __forceinline__ f32x4 mfma16(f16x8 a, f16x8 b, f32x4 c) {
    return __builtin_amdgcn_mfma_f32_16x16x32_f16(a, b, c, 0, 0, 0);
}
__device__ __forceinline__ uint32_t pkf16(float a, float b) {
    fp16x2 h = __builtin_amdgcn_cvt_pkrtz(a, b);
    return __builtin_bit_cast(uint32_t, h);
}

#define REP8(M) M(0)M(1)M(2)M(3)M(4)M(5)M(6)M(7)

// A-operand gather with per-column scale SC (weights transposed, z^T form):
// A[m=16T+l15][k=32F+8q+j] = SRC[k][16T+l15] * SC
#define GA(SRC, T, F, SC) (f16x8){ \
  (__fp16)((SRC)[(32*(F)+8*quad+0)*256 + 16*(T)+l15] * (SC)), \
  (__fp16)((SRC)[(32*(F)+8*quad+1)*256 + 16*(T)+l15] * (SC)), \
  (__fp16)((SRC)[(32*(F)+8*quad+2)*256 + 16*(T)+l15] * (SC)), \
  (__fp16)((SRC)[(32*(F)+8*quad+3)*256 + 16*(T)+l15] * (SC)), \
  (__fp16)((SRC)[(32*(F)+8*quad+4)*256 + 16*(T)+l15] * (SC)), \
  (__fp16)((SRC)[(32*(F)+8*quad+5)*256 + 16*(T)+l15] * (SC)), \
  (__fp16)((SRC)[(32*(F)+8*quad+6)*256 + 16*(T)+l15] * (SC)), \
  (__fp16)((SRC)[(32*(F)+8*quad+7)*256 + 16*(T)+l15] * (SC)) }

// Wave (l,h) owns zcols {64g + 32h + 16q' .. +15}: local j = 2g+q' -> tile Tg.
// Gate index = j>>1 (0:i 1:f 2:g 3:o). i/f/o columns+bias pre-scaled by -log2e
// so gates use exp2(z') directly (R16 fold, kept: load-time only, 0 reg cost).
#define DECLT(j) f16x8 uA##j##_0, uA##j##_1, wA##j##_0, wA##j##_1; f32x4 bias##j;
#define LOADT(j) { \
  const int Tg_ = ((j)>>1)*4 + 2*h + ((j)&1); \
  const float sc_ = (((j)>>1) == 2) ? 1.0f : -1.4426950408889634f; \
  uA##j##_0 = GA(Uw, Tg_, 0, sc_); uA##j##_1 = GA(Uw, Tg_, 1, sc_); \
  bias##j = (f32x4){ bw_[16*Tg_ + 4*quad + 0] * sc_, bw_[16*Tg_ + 4*quad + 1] * sc_, \
                     bw_[16*Tg_ + 4*quad + 2] * sc_, bw_[16*Tg_ + 4*quad + 3] * sc_ }; \
  if (l > 0) { wA##j##_0 = GA(Wsrc, Tg_, 0, sc_); wA##j##_1 = GA(Wsrc, Tg_, 1, sc_); } \
  else { wA##j##_0 = __builtin_bit_cast(f16x8, (f32x4){ \
           Wx0[16*Tg_+4*quad+0] * sc_, Wx0[16*Tg_+4*quad+1] * sc_, \
           Wx0[16*Tg_+4*quad+2] * sc_, Wx0[16*Tg_+4*quad+3] * sc_ }); \
         wA##j##_1 = wA##j##_0; } }

// W-side burst (partner-INdependent, accumulates into acc with bias as C):
#define MW0(j) acc##j = mfma16(wA##j##_0, xBp0, bias##j);
#define MW1(j) acc##j = mfma16(wA##j##_1, xBp1, acc##j);
#define MX(j)  acc##j = bias##j + __builtin_bit_cast(f32x4, wA##j##_0) * xvp4;
// U-side burst (recurrence):
#define MU0(j) acc##j = mfma16(uA##j##_0, hB0, acc##j);
#define MU1(j) acc##j = mfma16(uA##j##_1, hB1, acc##j);

// Gates: z' for i/f/o pre-scaled -> exp2 direct; g unscaled (relu only).
#define GATES(qp, Ai, Af, Ag, Ao, CST, SAVEK, HK) { \
  f32x4 ei_, ef_, eo_; \
  _Pragma("unroll") for (int r_ = 0; r_ < 4; ++r_) { \
    ei_[r_] = __builtin_amdgcn_exp2f(Ai[r_]); \
    ef_[r_] = __builtin_amdgcn_exp2f(Af[r_]); \
    eo_[r_] = __builtin_amdgcn_exp2f(Ao[r_]); \
  } \
  f32x4 si_, sf_, so_; \
  _Pragma("unroll") for (int r_ = 0; r_ < 4; ++r_) { \
    si_[r_] = __builtin_amdgcn_rcpf(1.0f + ei_[r_]); \
    sf_[r_] = __builtin_amdgcn_rcpf(1.0f + ef_[r_]); \
    so_[r_] = __builtin_amdgcn_rcpf(1.0f + eo_[r_]); \
  } \
  const f32x4 z4_ = {0.f, 0.f, 0.f, 0.f}; \
  f32x4 rg_ = __builtin_elementwise_max(Ag, z4_); \
  f32x4 cv_ = sf_ * CST + si_ * rg_; \
  CST = cv_; \
  f32x4 hv_ = so_ * __builtin_elementwise_max(cv_, z4_); \
  u32x2 pv_ = { pkf16(hv_[0], hv_[1]), pkf16(hv_[2], hv_[3]) }; \
  *(u32x2*)(hw_ + 16*(qp)) = pv_; \
  if (SAVEK) HK = hv_; }

#define GATE_SEG(tg_, SV_) { \
  __fp16* hw_ = hb_l + ((tg_)&7)*1152 + l15*72 + 32*h + 4*quad; \
  GATES(0, acc0, acc2, acc4, acc6, cst0, SV_, hK0) \
  GATES(1, acc1, acc3, acc5, acc7, cst1, SV_, hK1) }

// Spin-wait on a progress counter (workgroup-scope LDS atomic, cached locally).
#define WAITGE(cache, idx, need) \
  while ((cache) < (need)) \
    (cache) = __hip_atomic_load(&Pf[idx], __ATOMIC_ACQUIRE, __HIP_MEMORY_SCOPE_WORKGROUP);

// 64 blocks x 512 threads; block = 16 batch rows; 8 waves = 4 layers x 2 unit-halves.
// R17 = R14 async base (594us steady) + IN-STEP reorder: partner wait moved AFTER
// the 16 W-MFMAs (which don't need partner h) -> publish->detect latency hides
// under ~300cy of W issue. Accumulate into the SAME acc regs (bias as C) -- the
// R16 wacc set caused scratch spills (WRITE_SIZE 3204->4612 KB), this is 0-reg.
// exp2-fold kept; setprio dropped (unproven co-variable in R16 regression).
__global__ __launch_bounds__(512)
__attribute__((amdgpu_waves_per_eu(2, 2)))
void lstm_phase(
    const float* __restrict__ x,
    const float* __restrict__ Wx0, const float* __restrict__ U0, const float* __restrict__ b0,
    const float* __restrict__ Wx1, const float* __restrict__ U1, const float* __restrict__ b1,
    const float* __restrict__ Wx2, const float* __restrict__ U2, const float* __restrict__ b2,
    const float* __restrict__ Wx3, const float* __restrict__ U3, const float* __restrict__ b3,
    const float* __restrict__ Wd,  const float* __restrict__ bd,
    float* __restrict__ out)
{
    // dwords: hbuf f16 [0,18432) | x_s f32 [18432,27136) | red [27136,27168) | P [27168,27176)
    extern __shared__ uint32_t smem[];
    __fp16* hb16 = (__fp16*)smem;              // [l][slot8][row 16][unit 64 pad 72]
    float*  xs   = (float*)(smem + 18432);     // [t][17]
    float*  red  = (float*)(smem + 27136);     // [2][16] epilogue partials
    int*    Pf   = (int*)(smem + 27168);       // [8] per-wave progress counters

    const int tid  = threadIdx.x;
    const int lane = tid & 63;
    const int l15  = lane & 15;
    const int quad = lane >> 4;
    const int wv   = tid >> 6;
    const int l    = wv >> 1;                  // layer
    const int h    = wv & 1;                   // unit-half
    const int b0i  = blockIdx.x * 16;

    // ---- staging: zero hbuf + flags, stage x ----
    for (int i = tid; i < 27176; i += 512) smem[i] = 0;
    __syncthreads();
    for (int i = tid; i < 16 * TT; i += 512) {
        int row = i >> 9, t_ = i & (TT - 1);
        xs[t_ * 17 + row] = x[(b0i + row) * TT + t_];
    }

    const float* Uw   = (l == 0) ? U0 : (l == 1) ? U1 : (l == 2) ? U2 : U3;
    const float* bw_  = (l == 0) ? b0 : (l == 1) ? b1 : (l == 2) ? b2 : b3;
    const float* Wsrc = (l == 1) ? Wx1 : (l == 2) ? Wx2 : (l == 3) ? Wx3 : U0;

    REP8(DECLT)
    REP8(LOADT)

    f32x4 acc0, acc1, acc2, acc3, acc4, acc5, acc6, acc7;
    f32x4 cst0 = {0,0,0,0}, cst1 = {0,0,0,0};
    f32x4 hK0  = {0,0,0,0}, hK1  = {0,0,0,0};

    __fp16* hb_l  = hb16 + l * 9216;           // own buffer (8 slots x 1152 f16)
    const __fp16* hb_in = hb16 + (l > 0 ? (l - 1) * 9216 : 0);

    __syncthreads();

    float xvp = 0.f;
    if (l == 0) xvp = xs[l15];                 // layer-0 operand for t=0

    int pA0 = 0, pA1 = 0, pP = 0, pC0 = 0, pC1 = 0;   // cached counter values

    for (int t = 0; t < TT; ++t) {
        // ---- W-phase: partner-independent, hides publish->detect latency ----
        if (l > 0) {
            WAITGE(pA0, 2*l - 2, t + 1)
            WAITGE(pA1, 2*l - 1, t + 1)
            const __fp16* xp_ = hb_in + (t & 7) * 1152 + l15 * 72 + 8 * quad;
            f16x8 xBp0 = *(const f16x8*)xp_;
            f16x8 xBp1 = *(const f16x8*)(xp_ + 32);
            REP8(MW0)
            REP8(MW1)
        } else {
            f32x4 xvp4 = {xvp, xvp, xvp, xvp};
            REP8(MX)
        }
        // ---- slack guards + partner wait (detect hidden under W burst) ----
        if (l < 3 && t >= 8) {                 // ring-reuse guard (slot t&7 = h(t-8))
            WAITGE(pC0, 2*l + 2, t - 7)
            WAITGE(pC1, 2*l + 3, t - 7)
        }
        if (t > 0) WAITGE(pP, 2*l + 1 - h, t)
        // ---- U-phase: recurrence ----
        {
            const __fp16* hp_ = hb_l + ((t - 1) & 7) * 1152 + l15 * 72 + 8 * quad;
            f16x8 hB0 = *(const f16x8*)hp_;
            f16x8 hB1 = *(const f16x8*)(hp_ + 32);
            REP8(MU0)
            REP8(MU1)
        }
        // ---- gates + publish ----
        {
            const bool sv_ = (l == 3) && (t == TT - 1);
            GATE_SEG(t, sv_)
        }
        __hip_atomic_store(&Pf[2*l + h], t + 1, __ATOMIC_RELEASE, __HIP_MEMORY_SCOPE_WORKGROUP);
        if (l == 0 && t + 1 < TT) xvp = xs[(t + 1) * 17 + l15];
    }

    __syncthreads();

    // dense epilogue: waves (3,h); lane holds h[511] f32 for units 32h+16q'+4quad+r, row l15
    if (l == 3) {
        float p = 0.f;
        #pragma unroll
        for (int r = 0; r < 4; ++r) {
            p += hK0[r] * Wd[32 * h + 4 * quad + r];
            p += hK1[r] * Wd[32 * h + 16 + 4 * quad + r];
        }
        p += __shfl_down(p, 32, 64);
        p += __shfl_down(p, 16, 64);
        if (lane < 16) red[h * 16 + lane] = p;
    }
    __syncthreads();
    if (wv == 6 && lane < 16) out[b0i + lane] = red[lane] + red[16 + lane] + bd[0];
}

extern "C" void kernel_launch(void* const* d_in, const int* in_sizes, int n_in,
                              void* d_out, int out_size, void* d_ws, size_t ws_size,
                              hipStream_t stream) {
    const float* x   = (const float*)d_in[0];
    const float* Wx0 = (const float*)d_in[1];
    const float* U0  = (const float*)d_in[2];
    const float* b0  = (const float*)d_in[3];
    const float* Wx1 = (const float*)d_in[4];
    const float* U1  = (const float*)d_in[5];
    const float* b1  = (const float*)d_in[6];
    const float* Wx2 = (const float*)d_in[7];
    const float* U2  = (const float*)d_in[8];
    const float* b2  = (const float*)d_in[9];
    const float* Wx3 = (const float*)d_in[10];
    const float* U3  = (const float*)d_in[11];
    const float* b3  = (const float*)d_in[12];
    const float* Wd  = (const float*)d_in[13];
    const float* bd  = (const float*)d_in[14];
    float* out = (float*)d_out;

    static const int kLds = 27176 * 4;   // 108704 B dynamic LDS
    (void)hipFuncSetAttribute((const void*)lstm_phase,
                              hipFuncAttributeMaxDynamicSharedMemorySize, kLds);
    hipLaunchKernelGGL(lstm_phase, dim3(64), dim3(512), kLds, stream,
                       x, Wx0, U0, b0, Wx1, U1, b1, Wx2, U2, b2, Wx3, U3, b3,
                       Wd, bd, out);
}